// Round 1
// 537.271 us; speedup vs baseline: 1.0042x; 1.0042x over previous
//
#include <hip/hip_runtime.h>

typedef __bf16 bf16;
typedef __bf16 bf16x4 __attribute__((ext_vector_type(4)));
typedef __bf16 bf16x8 __attribute__((ext_vector_type(8)));
typedef float floatx4 __attribute__((ext_vector_type(4)));

#define NN 512
#define CC 128
#define NROW (NN*NN)   // 262144 rows

__device__ __forceinline__ void async16(void* lds, const void* g) {
    __builtin_amdgcn_global_load_lds((const __attribute__((address_space(1))) void*)g,
                                     (__attribute__((address_space(3))) void*)lds, 16, 0, 0);
}
__device__ __forceinline__ void wait_vm0() {
    asm volatile("s_waitcnt vmcnt(0)" ::: "memory");
}
__device__ __forceinline__ float sigmoidf(float x) {
    return __builtin_amdgcn_rcpf(1.f + __expf(-x));
}

// ---------------- setup: W' = W*nw (640x128 bf16), t1=sum(nw*W), t2=sum(nb*W); same for p_out ----------------
__global__ void setup_kernel(const float* __restrict__ nin_w, const float* __restrict__ nin_b,
                             const float* __restrict__ g_in_w, const float* __restrict__ p_in_w,
                             const float* __restrict__ g_out_w,
                             const float* __restrict__ nout_w, const float* __restrict__ nout_b,
                             const float* __restrict__ p_out_w,
                             bf16* __restrict__ Wall, float* __restrict__ T1, float* __restrict__ T2,
                             bf16* __restrict__ Pp, float* __restrict__ S1, float* __restrict__ S2) {
    int r = blockIdx.x * 256 + threadIdx.x;
    if (r < 640) {
        const float* src = (r < 256) ? (g_in_w + r*CC)
                         : (r < 512) ? (p_in_w + (r-256)*CC)
                                     : (g_out_w + (r-512)*CC);
        float t1 = 0.f, t2 = 0.f;
        for (int c = 0; c < CC; ++c) {
            float wv = src[c];
            float wn = nin_w[c];
            float bn = nin_b[c];
            Wall[r*CC + c] = (bf16)(wv * wn);
            t1 += wn * wv;
            t2 += bn * wv;
        }
        T1[r] = t1; T2[r] = t2;
    } else if (r < 768) {
        int d = r - 640;
        const float* src = p_out_w + d*CC;
        float t1 = 0.f, t2 = 0.f;
        for (int c = 0; c < CC; ++c) {
            float wv = src[c];
            float wn = nout_w[c];
            float bn = nout_b[c];
            Pp[d*CC + c] = (bf16)(wv * wn);
            t1 += wn * wv;
            t2 += bn * wv;
        }
        S1[d] = t1; S2[d] = t2;
    }
}

// ---------------- k1: fused LN-in + [g_in|p_in|g_out] projections ----------------
// Rewrite: x -> registers (no fp32 LDS), stats from regs, bf16 converted ONCE into
// a 16KB swizzled XN tile; frag reads conflict-free; gate stores via transpose buffer.
__global__ __launch_bounds__(256) void k1_ln_proj(
        const float* __restrict__ x, const bf16* __restrict__ Wall,
        const float* __restrict__ T1, const float* __restrict__ T2,
        bf16* __restrict__ a_t, bf16* __restrict__ b_t, bf16* __restrict__ gate) {
    __shared__ char  XNb[16384];       // [64 rows][256B bf16], 16B chunks stored at p = c16 ^ (row&15)
    __shared__ float MU[64], RS[64];
    // transpose buffers alias into XNb after frag loads: 3072B per wave

    const int t    = threadIdx.x;
    const int w    = t >> 6, lane = t & 63;
    const int col  = lane & 15, quad = lane >> 4;
    const long r0  = (long)blockIdx.x * 64;

    // ---- load 32 floats/thread straight to registers (4 threads per row)
    const int row  = t >> 2;           // 0..63
    const int part = t & 3;
    const float* xr = x + (r0 + row) * CC;
    floatx4 f[8];
#pragma unroll
    for (int j = 0; j < 8; ++j)
        f[j] = *(const floatx4*)(xr + (j*4 + part)*4);   // 4-float chunk c4 = j*4+part

    // ---- LN stats from registers (4 lanes per row, adjacent)
    {
        float sum = 0.f, ss = 0.f;
#pragma unroll
        for (int j = 0; j < 8; ++j)
#pragma unroll
            for (int e = 0; e < 4; ++e) { float v = f[j][e]; sum += v; ss += v*v; }
        sum += __shfl_xor(sum, 1, 64); ss += __shfl_xor(ss, 1, 64);
        sum += __shfl_xor(sum, 2, 64); ss += __shfl_xor(ss, 2, 64);
        float mu  = sum * (1.f/128.f);
        float var = ss  * (1.f/128.f) - mu*mu;
        float rs  = rsqrtf(var + 1e-5f);
        if (part == 0) { MU[row] = mu; RS[row] = rs; }
    }

    // ---- convert once -> swizzled bf16 tile (conflict-free b64 writes)
#pragma unroll
    for (int j = 0; j < 8; ++j) {
        int c4   = j*4 + part;                  // 8B bf16 chunk id, cols c4*4..c4*4+3
        int c16  = c4 >> 1, half = c4 & 1;
        bf16x4 v;
        v[0] = (bf16)f[j][0]; v[1] = (bf16)f[j][1];
        v[2] = (bf16)f[j][2]; v[3] = (bf16)f[j][3];
        *(bf16x4*)(XNb + row*256 + ((c16 ^ (row & 15)) * 16) + half*8) = v;
    }
    __syncthreads();

    // ---- A fragments: one conflict-free b128 read per frag (16/thread)
    bf16x8 af[4][4];
#pragma unroll
    for (int mt = 0; mt < 4; ++mt) {
        int rr = mt*16 + col;
#pragma unroll
        for (int s = 0; s < 4; ++s)
            af[mt][s] = *(const bf16x8*)(XNb + rr*256 + (((s*4 + quad) ^ (rr & 15)) * 16));
    }
    __syncthreads();                   // XN dead -> reuse as transpose buffers
    char* TBw = XNb + w*3072;          // pg: [c=col][r] stride 144B; gate: [r][c] stride 48B

    // ---- GEMM: jobs 0..15 = pg (g&p cols job*16..), jobs 16..23 = gate cols
    for (int jj = 0; jj < 6; ++jj) {
        int job = w + jj*4;
        if (job < 16) {
            bf16x8 bg[4], bp[4];
            for (int s = 0; s < 4; ++s) {
                bg[s] = *(const bf16x8*)(Wall + (      job*16 + col)*CC + s*32 + quad*8);
                bp[s] = *(const bf16x8*)(Wall + (256 + job*16 + col)*CC + s*32 + quad*8);
            }
            int dg = job*16 + col, dp = 256 + job*16 + col;
            float t1g = T1[dg], t2g = T2[dg], t1p = T1[dp], t2p = T2[dp];
            bf16* dst = (job < 8) ? a_t : b_t;
            int cbase = (job < 8 ? job : job - 8) * 16;
            for (int mt = 0; mt < 4; ++mt) {
                floatx4 ag = {0.f,0.f,0.f,0.f}, ap = {0.f,0.f,0.f,0.f};
            #pragma unroll
                for (int s = 0; s < 4; ++s) {
                    ag = __builtin_amdgcn_mfma_f32_16x16x32_bf16(af[mt][s], bg[s], ag, 0, 0, 0);
                    ap = __builtin_amdgcn_mfma_f32_16x16x32_bf16(af[mt][s], bp[s], ap, 0, 0, 0);
                }
                bf16x4 pk;
            #pragma unroll
                for (int reg = 0; reg < 4; ++reg) {
                    int m = mt*16 + quad*4 + reg;
                    float rs = RS[m], mu = MU[m];
                    float g = rs*ag[reg] - rs*mu*t1g + t2g;
                    float p = rs*ap[reg] - rs*mu*t1p + t2p;
                    pk[reg] = (bf16)(p * sigmoidf(g));
                }
                // wave-private transpose buffer: [c=col][r = mt*16+quad*4 ..+3]
                *(bf16x4*)(TBw + col*144 + mt*32 + quad*8) = pk;
            }
            // read back transposed: lane -> c = lane>>2, two 8-row chunks
            {
                int c  = lane >> 2;
                int c0 = lane & 3, c1 = (lane & 3) + 4;
                bf16x8 r0v = *(const bf16x8*)(TBw + c*144 + c0*16);
                bf16x8 r1v = *(const bf16x8*)(TBw + c*144 + c1*16);
                bf16* base = dst + (long)(cbase + c) * NROW + r0;
                *(bf16x8*)(base + c0*8) = r0v;
                *(bf16x8*)(base + c1*8) = r1v;
            }
        } else {
            int gc = job - 16;
            bf16x8 bgt[4];
            for (int s = 0; s < 4; ++s)
                bgt[s] = *(const bf16x8*)(Wall + (512 + gc*16 + col)*CC + s*32 + quad*8);
            int dd = 512 + gc*16 + col;
            float t1 = T1[dd], t2 = T2[dd];
            for (int mt = 0; mt < 4; ++mt) {
                floatx4 ac = {0.f,0.f,0.f,0.f};
            #pragma unroll
                for (int s = 0; s < 4; ++s)
                    ac = __builtin_amdgcn_mfma_f32_16x16x32_bf16(af[mt][s], bgt[s], ac, 0, 0, 0);
            #pragma unroll
                for (int reg = 0; reg < 4; ++reg) {
                    int m = mt*16 + quad*4 + reg;
                    float rs = RS[m], mu = MU[m];
                    float g = rs*ac[reg] - rs*mu*t1 + t2;
                    *(bf16*)(TBw + m*48 + col*2) = (bf16)sigmoidf(g);  // [r][c] stride 48B
                }
            }
            // read back row-major: lane = row, 16 cols = 2x16B; stores 2x16B per lane
            {
                bf16x8 g0 = *(const bf16x8*)(TBw + lane*48 + 0);
                bf16x8 g1 = *(const bf16x8*)(TBw + lane*48 + 16);
                bf16* gdst = gate + (r0 + lane)*CC + gc*16;
                *(bf16x8*)(gdst + 0) = g0;
                *(bf16x8*)(gdst + 8) = g1;
            }
        }
    }
}

// ---------------- k2: tri[c] = A_c * B_c^T  (128 independent 512^3 bf16 GEMMs), 256x128 tiles ----------------
__global__ __launch_bounds__(256, 2) void k2_tri(
        const bf16* __restrict__ a_t, const bf16* __restrict__ b_t, bf16* __restrict__ tri) {
    __shared__ char As[16384], Bs[8192];   // [rows][32 bf16], 16B chunks swizzled p = c ^ ((row>>2)&3)
    const int t    = threadIdx.x;
    const int w    = t >> 6, lane = t & 63;
    const int col  = lane & 15, quad = lane >> 4;
    const int c    = blockIdx.y;
    const int i0   = (blockIdx.x >> 2) * 256, j0 = (blockIdx.x & 3) * 128;
    const char* Ac = (const char*)(a_t + (long)c * NROW);
    const char* Bc = (const char*)(b_t + (long)c * NROW);
    const int wm = w * 64;                 // wave tile: 64 m x 128 n

    floatx4 acc[4][8];
    for (int mt = 0; mt < 4; ++mt)
        for (int nt = 0; nt < 8; ++nt) { floatx4 z = {0.f,0.f,0.f,0.f}; acc[mt][nt] = z; }

    for (int k0 = 0; k0 < 512; k0 += 32) {
        __syncthreads();
        for (int q = 0; q < 4; ++q) {
            int L = q*4096 + t*16;
            int row = L >> 6, p = (L >> 4) & 3;
            int cl = p ^ ((row >> 2) & 3);
            async16(As + L, Ac + (i0 + row)*1024 + k0*2 + cl*16);
        }
        for (int q = 0; q < 2; ++q) {
            int L = q*4096 + t*16;
            int row = L >> 6, p = (L >> 4) & 3;
            int cl = p ^ ((row >> 2) & 3);
            async16(Bs + L, Bc + (j0 + row)*1024 + k0*2 + cl*16);
        }
        wait_vm0();
        __syncthreads();
        bf16x8 afr[4], bfr[8];
        for (int mt = 0; mt < 4; ++mt) {
            int row = wm + mt*16 + col;
            afr[mt] = *(const bf16x8*)(As + row*64 + ((quad ^ ((row>>2)&3))*16));
        }
        for (int nt = 0; nt < 8; ++nt) {
            int row = nt*16 + col;
            bfr[nt] = *(const bf16x8*)(Bs + row*64 + ((quad ^ ((row>>2)&3))*16));
        }
        for (int mt = 0; mt < 4; ++mt)
            for (int nt = 0; nt < 8; ++nt)
                acc[mt][nt] = __builtin_amdgcn_mfma_f32_16x16x32_bf16(afr[mt], bfr[nt], acc[mt][nt], 0, 0, 0);
    }
    bf16* Tc = tri + (long)c * NROW;
    for (int mt = 0; mt < 4; ++mt)
        for (int nt = 0; nt < 8; ++nt)
            for (int reg = 0; reg < 4; ++reg) {
                int m = i0 + wm + mt*16 + quad*4 + reg;
                int n = j0 + nt*16 + col;
                Tc[m*512 + n] = (bf16)acc[mt][nt][reg];
            }
}

// ---------------- k3: out = (LN(tri) @ Pp^T) * gate, LN folded into epilogue (fp32 out) ----------------
__global__ __launch_bounds__(256) void k3_out(
        const bf16* __restrict__ tri, const bf16* __restrict__ Pp,
        const float* __restrict__ S1, const float* __restrict__ S2,
        const bf16* __restrict__ gate, float* __restrict__ out) {
    __shared__ char  AS[128*272];         // [128 r][128 c bf16], row stride 272B (16-aligned, bank-spread)
    __shared__ float MU[128], RS[128];
    const int t    = threadIdx.x;
    const int w    = t >> 6, lane = t & 63;
    const int col  = lane & 15, quad = lane >> 4;
    const long r0  = (long)blockIdx.x * 128;

    // ---- stage tri tile: gather 4 c-planes per lane (coalesced 2B loads), ds_write_b64
    for (int it = 0; it < 16; ++it) {
        int rl = (it & 1)*64 + (t & 63);
        int cq = (it >> 1)*4 + (t >> 6);
        const bf16* src = tri + (long)(cq*4) * NROW + r0 + rl;
        bf16x4 v;
        v[0] = src[0];
        v[1] = src[NROW];
        v[2] = src[2*NROW];
        v[3] = src[3*NROW];
        *(bf16x4*)(AS + rl*272 + cq*8) = v;
    }
    __syncthreads();

    // ---- LN stats
    {
        int row = t >> 1, half = t & 1;
        float sum = 0.f, ss = 0.f;
        for (int j = 0; j < 8; ++j) {
            bf16x8 v = *(const bf16x8*)(AS + row*272 + (half*8 + j)*16);
            for (int jj = 0; jj < 8; ++jj) { float f = (float)v[jj]; sum += f; ss += f*f; }
        }
        sum += __shfl_xor(sum, 1, 64);
        ss  += __shfl_xor(ss, 1, 64);
        float mu  = sum * (1.f/128.f);
        float var = ss  * (1.f/128.f) - mu*mu;
        float rs  = rsqrtf(var + 1e-5f);
        if (half == 0) { MU[row] = mu; RS[row] = rs; }
    }
    __syncthreads();

    const int wm = (w >> 1)*64, wn = (w & 1)*64;
    floatx4 acc[4][4];
    for (int mt = 0; mt < 4; ++mt)
        for (int nt = 0; nt < 4; ++nt) { floatx4 z = {0.f,0.f,0.f,0.f}; acc[mt][nt] = z; }

    for (int s = 0; s < 4; ++s) {
        bf16x8 bfr[4];
        for (int nt = 0; nt < 4; ++nt)
            bfr[nt] = *(const bf16x8*)(Pp + (wn + nt*16 + col)*CC + s*32 + quad*8);
        for (int mt = 0; mt < 4; ++mt) {
            int row = wm + mt*16 + col;
            bf16x8 afr = *(const bf16x8*)(AS + row*272 + s*64 + quad*16);
            for (int nt = 0; nt < 4; ++nt)
                acc[mt][nt] = __builtin_amdgcn_mfma_f32_16x16x32_bf16(afr, bfr[nt], acc[mt][nt], 0, 0, 0);
        }
    }

    for (int mt = 0; mt < 4; ++mt)
        for (int nt = 0; nt < 4; ++nt) {
            int n = wn + nt*16 + col;
            float s1 = S1[n], s2 = S2[n];
            for (int reg = 0; reg < 4; ++reg) {
                int m = wm + mt*16 + quad*4 + reg;
                float rs = RS[m], mu = MU[m];
                float v  = rs*acc[mt][nt][reg] - rs*mu*s1 + s2;
                float gt = (float)gate[(r0 + m)*CC + n];
                out[(r0 + m)*CC + n] = v * gt;
            }
        }
}

extern "C" void kernel_launch(void* const* d_in, const int* in_sizes, int n_in,
                              void* d_out, int out_size, void* d_ws, size_t ws_size,
                              hipStream_t stream) {
    const float* x       = (const float*)d_in[0];
    const float* nin_w   = (const float*)d_in[1];
    const float* nin_b   = (const float*)d_in[2];
    const float* g_in_w  = (const float*)d_in[3];
    const float* p_in_w  = (const float*)d_in[4];
    const float* g_out_w = (const float*)d_in[5];
    const float* nout_w  = (const float*)d_in[6];
    const float* nout_b  = (const float*)d_in[7];
    const float* p_out_w = (const float*)d_in[8];

    char* ws = (char*)d_ws;
    bf16*  Wall = (bf16*)(ws);                      // 640*128*2 = 163840
    float* T1   = (float*)(ws + 163840);            // 2560
    float* T2   = (float*)(ws + 166400);            // 2560
    bf16*  Pp   = (bf16*)(ws + 168960);             // 32768
    float* S1   = (float*)(ws + 201728);            // 512
    float* S2   = (float*)(ws + 202240);            // 512
    const long BIG = 67108864L;                     // 262144*128*2 bytes
    bf16* a_t  = (bf16*)(ws + 204800);
    bf16* b_t  = (bf16*)(ws + 204800 + BIG);
    bf16* gate = (bf16*)(ws + 204800 + 2*BIG);
    bf16* tri  = (bf16*)(ws + 204800 + 3*BIG);
    float* outp = (float*)d_out;

    setup_kernel<<<3, 256, 0, stream>>>(nin_w, nin_b, g_in_w, p_in_w, g_out_w,
                                        nout_w, nout_b, p_out_w,
                                        Wall, T1, T2, Pp, S1, S2);
    k1_ln_proj<<<4096, 256, 0, stream>>>(x, Wall, T1, T2, a_t, b_t, gate);
    k2_tri<<<dim3(8, 128), 256, 0, stream>>>(a_t, b_t, tri);
    k3_out<<<2048, 256, 0, stream>>>(tri, Pp, S1, S2, gate, outp);
}

// Round 2
// 515.382 us; speedup vs baseline: 1.0468x; 1.0425x over previous
//
#include <hip/hip_runtime.h>

typedef __bf16 bf16;
typedef __bf16 bf16x4 __attribute__((ext_vector_type(4)));
typedef __bf16 bf16x8 __attribute__((ext_vector_type(8)));
typedef float floatx4 __attribute__((ext_vector_type(4)));

#define NN 512
#define CC 128
#define NROW (NN*NN)   // 262144 rows

__device__ __forceinline__ void async16(void* lds, const void* g) {
    __builtin_amdgcn_global_load_lds((const __attribute__((address_space(1))) void*)g,
                                     (__attribute__((address_space(3))) void*)lds, 16, 0, 0);
}
__device__ __forceinline__ void wait_vm0() {
    asm volatile("s_waitcnt vmcnt(0)" ::: "memory");
}
__device__ __forceinline__ float sigmoidf(float x) {
    return __builtin_amdgcn_rcpf(1.f + __expf(-x));
}

// ---------------- setup: W' = W*nw (640x128 bf16), t1=sum(nw*W), t2=sum(nb*W); same for p_out ----------------
__global__ void setup_kernel(const float* __restrict__ nin_w, const float* __restrict__ nin_b,
                             const float* __restrict__ g_in_w, const float* __restrict__ p_in_w,
                             const float* __restrict__ g_out_w,
                             const float* __restrict__ nout_w, const float* __restrict__ nout_b,
                             const float* __restrict__ p_out_w,
                             bf16* __restrict__ Wall, float* __restrict__ T1, float* __restrict__ T2,
                             bf16* __restrict__ Pp, float* __restrict__ S1, float* __restrict__ S2) {
    int r = blockIdx.x * 256 + threadIdx.x;
    if (r < 640) {
        const float* src = (r < 256) ? (g_in_w + r*CC)
                         : (r < 512) ? (p_in_w + (r-256)*CC)
                                     : (g_out_w + (r-512)*CC);
        float t1 = 0.f, t2 = 0.f;
        for (int c = 0; c < CC; ++c) {
            float wv = src[c];
            float wn = nin_w[c];
            float bn = nin_b[c];
            Wall[r*CC + c] = (bf16)(wv * wn);
            t1 += wn * wv;
            t2 += bn * wv;
        }
        T1[r] = t1; T2[r] = t2;
    } else if (r < 768) {
        int d = r - 640;
        const float* src = p_out_w + d*CC;
        float t1 = 0.f, t2 = 0.f;
        for (int c = 0; c < CC; ++c) {
            float wv = src[c];
            float wn = nout_w[c];
            float bn = nout_b[c];
            Pp[d*CC + c] = (bf16)(wv * wn);
            t1 += wn * wv;
            t2 += bn * wv;
        }
        S1[d] = t1; S2[d] = t2;
    }
}

// ---------------- k1: fused LN-in + [g_in|p_in|g_out] projections ----------------
// A-fragments reloaded from LDS per job (frees 64 VGPRs -> occupancy); transpose
// buffers in separate LDS (one barrier total).
__global__ __launch_bounds__(256) void k1_ln_proj(
        const float* __restrict__ x, const bf16* __restrict__ Wall,
        const float* __restrict__ T1, const float* __restrict__ T2,
        bf16* __restrict__ a_t, bf16* __restrict__ b_t, bf16* __restrict__ gate) {
    __shared__ char  XNb[16384];       // [64 rows][256B bf16], 16B chunks stored at p = c16 ^ (row&15)
    __shared__ char  TB[12288];        // 4 waves x 3072B transpose buffers
    __shared__ float MU[64], RS[64];

    const int t    = threadIdx.x;
    const int w    = t >> 6, lane = t & 63;
    const int col  = lane & 15, quad = lane >> 4;
    const long r0  = (long)blockIdx.x * 64;

    // ---- load 32 floats/thread straight to registers (4 threads per row)
    const int row  = t >> 2;           // 0..63
    const int part = t & 3;
    const float* xr = x + (r0 + row) * CC;
    floatx4 f[8];
#pragma unroll
    for (int j = 0; j < 8; ++j)
        f[j] = *(const floatx4*)(xr + (j*4 + part)*4);   // 4-float chunk c4 = j*4+part

    // ---- LN stats from registers (4 lanes per row, adjacent)
    {
        float sum = 0.f, ss = 0.f;
#pragma unroll
        for (int j = 0; j < 8; ++j)
#pragma unroll
            for (int e = 0; e < 4; ++e) { float v = f[j][e]; sum += v; ss += v*v; }
        sum += __shfl_xor(sum, 1, 64); ss += __shfl_xor(ss, 1, 64);
        sum += __shfl_xor(sum, 2, 64); ss += __shfl_xor(ss, 2, 64);
        float mu  = sum * (1.f/128.f);
        float var = ss  * (1.f/128.f) - mu*mu;
        float rs  = rsqrtf(var + 1e-5f);
        if (part == 0) { MU[row] = mu; RS[row] = rs; }
    }

    // ---- convert once -> swizzled bf16 tile (conflict-free b64 writes)
#pragma unroll
    for (int j = 0; j < 8; ++j) {
        int c4   = j*4 + part;                  // 8B bf16 chunk id, cols c4*4..c4*4+3
        int c16  = c4 >> 1, half = c4 & 1;
        bf16x4 v;
        v[0] = (bf16)f[j][0]; v[1] = (bf16)f[j][1];
        v[2] = (bf16)f[j][2]; v[3] = (bf16)f[j][3];
        *(bf16x4*)(XNb + row*256 + ((c16 ^ (row & 15)) * 16) + half*8) = v;
    }
    __syncthreads();

    char* TBw = TB + w*3072;           // pg: [c=col][r] stride 144B; gate: [r][c] stride 48B

    // ---- GEMM: jobs 0..15 = pg (g&p cols job*16..), jobs 16..23 = gate cols
    for (int jj = 0; jj < 6; ++jj) {
        int job = w + jj*4;
        if (job < 16) {
            bf16x8 bg[4], bp[4];
            for (int s = 0; s < 4; ++s) {
                bg[s] = *(const bf16x8*)(Wall + (      job*16 + col)*CC + s*32 + quad*8);
                bp[s] = *(const bf16x8*)(Wall + (256 + job*16 + col)*CC + s*32 + quad*8);
            }
            int dg = job*16 + col, dp = 256 + job*16 + col;
            float t1g = T1[dg], t2g = T2[dg], t1p = T1[dp], t2p = T2[dp];
            bf16* dst = (job < 8) ? a_t : b_t;
            int cbase = (job < 8 ? job : job - 8) * 16;
            for (int mt = 0; mt < 4; ++mt) {
                int rr = mt*16 + col;
                bf16x8 afm[4];
            #pragma unroll
                for (int s = 0; s < 4; ++s)
                    afm[s] = *(const bf16x8*)(XNb + rr*256 + (((s*4 + quad) ^ (rr & 15)) * 16));
                floatx4 ag = {0.f,0.f,0.f,0.f}, ap = {0.f,0.f,0.f,0.f};
            #pragma unroll
                for (int s = 0; s < 4; ++s) {
                    ag = __builtin_amdgcn_mfma_f32_16x16x32_bf16(afm[s], bg[s], ag, 0, 0, 0);
                    ap = __builtin_amdgcn_mfma_f32_16x16x32_bf16(afm[s], bp[s], ap, 0, 0, 0);
                }
                bf16x4 pk;
            #pragma unroll
                for (int reg = 0; reg < 4; ++reg) {
                    int m = mt*16 + quad*4 + reg;
                    float rs = RS[m], mu = MU[m];
                    float g = rs*ag[reg] - rs*mu*t1g + t2g;
                    float p = rs*ap[reg] - rs*mu*t1p + t2p;
                    pk[reg] = (bf16)(p * sigmoidf(g));
                }
                // wave-private transpose buffer: [c=col][r = mt*16+quad*4 ..+3]
                *(bf16x4*)(TBw + col*144 + mt*32 + quad*8) = pk;
            }
            // read back transposed: lane -> c = lane>>2, two 8-row chunks
            {
                int c  = lane >> 2;
                int c0 = lane & 3, c1 = (lane & 3) + 4;
                bf16x8 r0v = *(const bf16x8*)(TBw + c*144 + c0*16);
                bf16x8 r1v = *(const bf16x8*)(TBw + c*144 + c1*16);
                bf16* base = dst + (long)(cbase + c) * NROW + r0;
                *(bf16x8*)(base + c0*8) = r0v;
                *(bf16x8*)(base + c1*8) = r1v;
            }
        } else {
            int gc = job - 16;
            bf16x8 bgt[4];
            for (int s = 0; s < 4; ++s)
                bgt[s] = *(const bf16x8*)(Wall + (512 + gc*16 + col)*CC + s*32 + quad*8);
            int dd = 512 + gc*16 + col;
            float t1 = T1[dd], t2 = T2[dd];
            for (int mt = 0; mt < 4; ++mt) {
                int rr = mt*16 + col;
                bf16x8 afm[4];
            #pragma unroll
                for (int s = 0; s < 4; ++s)
                    afm[s] = *(const bf16x8*)(XNb + rr*256 + (((s*4 + quad) ^ (rr & 15)) * 16));
                floatx4 ac = {0.f,0.f,0.f,0.f};
            #pragma unroll
                for (int s = 0; s < 4; ++s)
                    ac = __builtin_amdgcn_mfma_f32_16x16x32_bf16(afm[s], bgt[s], ac, 0, 0, 0);
            #pragma unroll
                for (int reg = 0; reg < 4; ++reg) {
                    int m = mt*16 + quad*4 + reg;
                    float rs = RS[m], mu = MU[m];
                    float g = rs*ac[reg] - rs*mu*t1 + t2;
                    *(bf16*)(TBw + m*48 + col*2) = (bf16)sigmoidf(g);  // [r][c] stride 48B
                }
            }
            // read back row-major: lane = row, 16 cols = 2x16B; stores 2x16B per lane
            {
                bf16x8 g0 = *(const bf16x8*)(TBw + lane*48 + 0);
                bf16x8 g1 = *(const bf16x8*)(TBw + lane*48 + 16);
                bf16* gdst = gate + (r0 + lane)*CC + gc*16;
                *(bf16x8*)(gdst + 0) = g0;
                *(bf16x8*)(gdst + 8) = g1;
            }
        }
    }
}

// ---------------- k2: tri[c] = A_c * B_c^T  (128 independent 512^3 bf16 GEMMs), 256x128 tiles ----------------
// 2-phase pipeline (stage next tile before compute, one vmcnt(0)+barrier per K-step)
// + c-affinity swizzle: all 8 tiles of a channel land on one XCD's L2.
__device__ __forceinline__ void k2_stage(char* Asb, char* Bsb, const char* Ac, const char* Bc,
                                         int i0, int j0, int k0, int t) {
    for (int q = 0; q < 4; ++q) {
        int L = q*4096 + t*16;
        int row = L >> 6, p = (L >> 4) & 3;
        int cl = p ^ ((row >> 2) & 3);
        async16(Asb + L, Ac + (i0 + row)*1024 + k0*2 + cl*16);
    }
    for (int q = 0; q < 2; ++q) {
        int L = q*4096 + t*16;
        int row = L >> 6, p = (L >> 4) & 3;
        int cl = p ^ ((row >> 2) & 3);
        async16(Bsb + L, Bc + (j0 + row)*1024 + k0*2 + cl*16);
    }
}

__global__ __launch_bounds__(256, 2) void k2_tri(
        const bf16* __restrict__ a_t, const bf16* __restrict__ b_t, bf16* __restrict__ tri) {
    __shared__ char As[2][16384], Bs[2][8192];
    const int t    = threadIdx.x;
    const int w    = t >> 6, lane = t & 63;
    const int col  = lane & 15, quad = lane >> 4;
    const int wg   = blockIdx.x;
    const int c    = (wg & 7) + ((wg >> 6) << 3);   // bijective; wg%8 fixed per c -> same XCD
    const int tile = (wg >> 3) & 7;
    const int i0   = (tile >> 2) * 256, j0 = (tile & 3) * 128;
    const char* Ac = (const char*)(a_t + (long)c * NROW);
    const char* Bc = (const char*)(b_t + (long)c * NROW);
    const int wm = w * 64;                 // wave tile: 64 m x 128 n

    floatx4 acc[4][8];
    for (int mt = 0; mt < 4; ++mt)
        for (int nt = 0; nt < 8; ++nt) { floatx4 z = {0.f,0.f,0.f,0.f}; acc[mt][nt] = z; }

    k2_stage(As[0], Bs[0], Ac, Bc, i0, j0, 0, t);
    wait_vm0();
    __syncthreads();

    int cur = 0;
    for (int kt = 0; kt < 16; ++kt) {
        if (kt < 15)
            k2_stage(As[cur^1], Bs[cur^1], Ac, Bc, i0, j0, (kt+1)*32, t);
        bf16x8 afr[4], bfr[8];
        for (int mt = 0; mt < 4; ++mt) {
            int row = wm + mt*16 + col;
            afr[mt] = *(const bf16x8*)(As[cur] + row*64 + ((quad ^ ((row>>2)&3))*16));
        }
        for (int nt = 0; nt < 8; ++nt) {
            int row = nt*16 + col;
            bfr[nt] = *(const bf16x8*)(Bs[cur] + row*64 + ((quad ^ ((row>>2)&3))*16));
        }
        for (int mt = 0; mt < 4; ++mt)
            for (int nt = 0; nt < 8; ++nt)
                acc[mt][nt] = __builtin_amdgcn_mfma_f32_16x16x32_bf16(afr[mt], bfr[nt], acc[mt][nt], 0, 0, 0);
        wait_vm0();
        __syncthreads();
        cur ^= 1;
    }
    bf16* Tc = tri + (long)c * NROW;
    for (int mt = 0; mt < 4; ++mt)
        for (int nt = 0; nt < 8; ++nt)
            for (int reg = 0; reg < 4; ++reg) {
                int m = i0 + wm + mt*16 + quad*4 + reg;
                int n = j0 + nt*16 + col;
                Tc[m*512 + n] = (bf16)acc[mt][nt][reg];
            }
}

// ---------------- k3: out = (LN(tri) @ Pp^T) * gate, LN folded into epilogue (fp32 out) ----------------
// Staging: coalesced bf16x8 loads (16B/lane) + LDS-transpose writes; chunk16 XOR
// swizzle (^ (row>>3)&3) applied on stage-write, LN-read and A-frag read.
__global__ __launch_bounds__(256) void k3_out(
        const bf16* __restrict__ tri, const bf16* __restrict__ Pp,
        const float* __restrict__ S1, const float* __restrict__ S2,
        const bf16* __restrict__ gate, float* __restrict__ out) {
    __shared__ char  AS[128*272];         // [128 r][128 c bf16], row stride 272B
    __shared__ float MU[128], RS[128];
    const int t    = threadIdx.x;
    const int w    = t >> 6, lane = t & 63;
    const int col  = lane & 15, quad = lane >> 4;
    const long r0  = (long)blockIdx.x * 128;

    // ---- stage tri tile: per lane 8x bf16x8 coalesced loads (4 c-planes x 8 rows x 2 iters)
    for (int it = 0; it < 2; ++it) {
        int grp = it*16 + (t >> 4);        // 8B slot index h = c0/4, 32 total
        int c0  = grp*4;
        int jb  = (t & 15)*8;
        const bf16* src = tri + (long)c0 * NROW + r0 + jb;
        bf16x8 p0 = *(const bf16x8*)(src);
        bf16x8 p1 = *(const bf16x8*)(src + NROW);
        bf16x8 p2 = *(const bf16x8*)(src + 2*NROW);
        bf16x8 p3 = *(const bf16x8*)(src + 3*NROW);
        int slot = grp ^ ((t & 3) << 1);   // h ^ (((row>>3)&3)<<1), row>>3 = t&15
    #pragma unroll
        for (int j = 0; j < 8; ++j) {
            bf16x4 v;
            v[0] = p0[j]; v[1] = p1[j]; v[2] = p2[j]; v[3] = p3[j];
            *(bf16x4*)(AS + (jb + j)*272 + slot*8) = v;
        }
    }
    __syncthreads();

    // ---- LN stats
    {
        int row = t >> 1, half = t & 1;
        float sum = 0.f, ss = 0.f;
        for (int j = 0; j < 8; ++j) {
            int ch = (half*8 + j) ^ ((row >> 3) & 3);
            bf16x8 v = *(const bf16x8*)(AS + row*272 + ch*16);
            for (int jj = 0; jj < 8; ++jj) { float f = (float)v[jj]; sum += f; ss += f*f; }
        }
        sum += __shfl_xor(sum, 1, 64);
        ss  += __shfl_xor(ss, 1, 64);
        float mu  = sum * (1.f/128.f);
        float var = ss  * (1.f/128.f) - mu*mu;
        float rs  = rsqrtf(var + 1e-5f);
        if (half == 0) { MU[row] = mu; RS[row] = rs; }
    }
    __syncthreads();

    const int wm = (w >> 1)*64, wn = (w & 1)*64;
    floatx4 acc[4][4];
    for (int mt = 0; mt < 4; ++mt)
        for (int nt = 0; nt < 4; ++nt) { floatx4 z = {0.f,0.f,0.f,0.f}; acc[mt][nt] = z; }

    for (int s = 0; s < 4; ++s) {
        bf16x8 bfr[4];
        for (int nt = 0; nt < 4; ++nt)
            bfr[nt] = *(const bf16x8*)(Pp + (wn + nt*16 + col)*CC + s*32 + quad*8);
        for (int mt = 0; mt < 4; ++mt) {
            int row = wm + mt*16 + col;
            int ch  = (s*4 + quad) ^ ((row >> 3) & 3);
            bf16x8 afr = *(const bf16x8*)(AS + row*272 + ch*16);
            for (int nt = 0; nt < 4; ++nt)
                acc[mt][nt] = __builtin_amdgcn_mfma_f32_16x16x32_bf16(afr, bfr[nt], acc[mt][nt], 0, 0, 0);
        }
    }

    for (int mt = 0; mt < 4; ++mt)
        for (int nt = 0; nt < 4; ++nt) {
            int n = wn + nt*16 + col;
            float s1 = S1[n], s2 = S2[n];
            for (int reg = 0; reg < 4; ++reg) {
                int m = wm + mt*16 + quad*4 + reg;
                float rs = RS[m], mu = MU[m];
                float v  = rs*acc[mt][nt][reg] - rs*mu*s1 + s2;
                float gt = (float)gate[(r0 + m)*CC + n];
                out[(r0 + m)*CC + n] = v * gt;
            }
        }
}

extern "C" void kernel_launch(void* const* d_in, const int* in_sizes, int n_in,
                              void* d_out, int out_size, void* d_ws, size_t ws_size,
                              hipStream_t stream) {
    const float* x       = (const float*)d_in[0];
    const float* nin_w   = (const float*)d_in[1];
    const float* nin_b   = (const float*)d_in[2];
    const float* g_in_w  = (const float*)d_in[3];
    const float* p_in_w  = (const float*)d_in[4];
    const float* g_out_w = (const float*)d_in[5];
    const float* nout_w  = (const float*)d_in[6];
    const float* nout_b  = (const float*)d_in[7];
    const float* p_out_w = (const float*)d_in[8];

    char* ws = (char*)d_ws;
    bf16*  Wall = (bf16*)(ws);                      // 640*128*2 = 163840
    float* T1   = (float*)(ws + 163840);            // 2560
    float* T2   = (float*)(ws + 166400);            // 2560
    bf16*  Pp   = (bf16*)(ws + 168960);             // 32768
    float* S1   = (float*)(ws + 201728);            // 512
    float* S2   = (float*)(ws + 202240);            // 512
    const long BIG = 67108864L;                     // 262144*128*2 bytes
    bf16* a_t  = (bf16*)(ws + 204800);
    bf16* b_t  = (bf16*)(ws + 204800 + BIG);
    bf16* gate = (bf16*)(ws + 204800 + 2*BIG);
    bf16* tri  = (bf16*)(ws + 204800 + 3*BIG);
    float* outp = (float*)d_out;

    setup_kernel<<<3, 256, 0, stream>>>(nin_w, nin_b, g_in_w, p_in_w, g_out_w,
                                        nout_w, nout_b, p_out_w,
                                        Wall, T1, T2, Pp, S1, S2);
    k1_ln_proj<<<4096, 256, 0, stream>>>(x, Wall, T1, T2, a_t, b_t, gate);
    k2_tri<<<1024, 256, 0, stream>>>(a_t, b_t, tri);
    k3_out<<<2048, 256, 0, stream>>>(tri, Pp, S1, S2, gate, outp);
}